// Round 7
// baseline (255.195 us; speedup 1.0000x reference)
//
#include <hip/hip_runtime.h>
#include <hip/hip_bf16.h>
#include <cstdint>

typedef __bf16 bf16x8 __attribute__((ext_vector_type(8)));
typedef float f32x4 __attribute__((ext_vector_type(4)));
typedef uint4 __attribute__((may_alias)) uint4a;

typedef __attribute__((address_space(3))) unsigned int   lds_u32;
typedef __attribute__((address_space(1))) const unsigned int gbl_u32;

#define BATCH 4
#define SEQ   2048
#define CDIM  1024
#define NH    16
#define HD    64
#define MROWS (BATCH*SEQ)   /* 8192 */

#define C1SCALE 0.18033688011112042f  /* Dh^-0.5 * log2(e), folded into Q */

__device__ __forceinline__ unsigned short f2bf(float f) {
    uint32_t u = __builtin_bit_cast(uint32_t, f);
    u += 0x7fffu + ((u >> 16) & 1u);
    return (unsigned short)(u >> 16);
}

// packed f32x2 -> bf16x2 (low = a, high = b), HW instr on gfx950
#if __has_builtin(__builtin_amdgcn_cvt_pk_bf16_f32)
typedef __bf16 bf16x2 __attribute__((ext_vector_type(2)));
__device__ __forceinline__ uint32_t pk2bf(float a, float b) {
    bf16x2 v = __builtin_amdgcn_cvt_pk_bf16_f32(a, b);
    return __builtin_bit_cast(uint32_t, v);
}
#else
__device__ __forceinline__ uint32_t pk2bf(float a, float b) {
    return (uint32_t)f2bf(a) | ((uint32_t)f2bf(b) << 16);
}
#endif

// async 16B/lane global->LDS (wave-uniform LDS base; HW writes base+lane*16)
__device__ __forceinline__ void g2l16(const unsigned short* g, unsigned short* l) {
    __builtin_amdgcn_global_load_lds((gbl_u32*)g, (lds_u32*)l, 16, 0, 0);
}

// ---------------- elementwise fp32 -> bf16 ----------------
__global__ void cvt_bf16_kernel(const float* __restrict__ in,
                                unsigned short* __restrict__ out, int n) {
    int i = (blockIdx.x * blockDim.x + threadIdx.x) * 4;
    if (i + 3 < n) {
        float4 v = *(const float4*)(in + i);
        uint2 o;
        o.x = pk2bf(v.x, v.y);
        o.y = pk2bf(v.z, v.w);
        *(uint2*)(out + i) = o;
    }
}

// ---------------- transpose + convert: in[R][Cc] fp32 -> out[Cc][R] bf16 ----
__global__ void transpose_cvt_kernel(const float* __restrict__ in,
                                     unsigned short* __restrict__ out,
                                     int R, int Cc) {
    __shared__ float tile[32][33];
    int c0 = blockIdx.x * 32, r0 = blockIdx.y * 32;
    int tx = threadIdx.x, ty = threadIdx.y;
    #pragma unroll
    for (int i = 0; i < 32; i += 8)
        tile[ty + i][tx] = in[(size_t)(r0 + ty + i) * Cc + c0 + tx];
    __syncthreads();
    #pragma unroll
    for (int i = 0; i < 32; i += 8)
        out[(size_t)(c0 + ty + i) * R + r0 + tx] = f2bf(tile[tx][ty + i]);
}

// ---------------- mask scan: per-batch compaction map ----------------------
__global__ void mask_scan_kernel(const int* __restrict__ mask,
                                 int* __restrict__ pfx, int* __restrict__ cnt) {
    __shared__ int s[256];
    int b = blockIdx.x, t = threadIdx.x;
    int keep[8], lc = 0;
    #pragma unroll
    for (int u = 0; u < 8; ++u) {
        keep[u] = (mask[b * SEQ + t * 8 + u] > 0) ? 0 : 1;
        lc += keep[u];
    }
    s[t] = lc;
    __syncthreads();
    for (int d = 1; d < 256; d <<= 1) {
        int w = (t >= d) ? s[t - d] : 0;
        __syncthreads();
        s[t] += w;
        __syncthreads();
    }
    int pos = s[t] - lc;
    #pragma unroll
    for (int u = 0; u < 8; ++u) {
        int idx = b * SEQ + t * 8 + u;
        pfx[idx] = keep[u] ? pos++ : -1;
    }
    if (t == 255) cnt[b] = s[255];
}

// ---------------- GEMM 1: qkv = xb @ Wqkv --------------------------------
// Q -> [B,H,N,Dh] PRE-SCALED by C1SCALE; K -> [B,H,j,Dh] compacted;
// V -> [B,H,Dh,j] compacted+T.
// LDS: stride 64 shorts, 16B-granule XOR swizzle (conflict-free reads).
#define BK 64

__global__ __launch_bounds__(256, 2)
void gemm_qkv_kernel(const unsigned short* __restrict__ A,
                     const unsigned short* __restrict__ Bt,
                     const int* __restrict__ pfx,
                     unsigned short* __restrict__ Q,
                     unsigned short* __restrict__ Kc,
                     unsigned short* __restrict__ Vct) {
    __shared__ __align__(16) unsigned short sA[128 * 64];
    __shared__ __align__(16) unsigned short sB[128 * 64];
    const int Kdim = 1024;
    int m0 = blockIdx.x * 128;
    int n0 = blockIdx.y * 128;
    int tid = threadIdx.x;
    int wave = tid >> 6, lane = tid & 63;
    int wm = (wave >> 1) * 64, wn = (wave & 1) * 64;
    int l15 = lane & 15, quad = lane >> 4;
    int lr = lane >> 3, lc8 = ((lane & 7) ^ lr) * 8;  // swizzled source col

    f32x4 acc[4][4] = {};

    for (int k0 = 0; k0 < Kdim; k0 += BK) {
        #pragma unroll
        for (int it = 0; it < 4; ++it) {
            int c = wave * 4 + it;            // chunk: 8 rows x 64 cols
            int gr = c * 8 + lr;
            g2l16(A  + (size_t)(m0 + gr) * Kdim + k0 + lc8, &sA[c * 512]);
            g2l16(Bt + (size_t)(n0 + gr) * Kdim + k0 + lc8, &sB[c * 512]);
        }
        __syncthreads();
        #pragma unroll
        for (int kk = 0; kk < BK; kk += 32) {
            bf16x8 af[4], bfr[4];
            #pragma unroll
            for (int i = 0; i < 4; ++i) {
                int r = wm + i * 16 + l15;
                int q = ((kk >> 3) + quad) ^ (r & 7);
                af[i] = __builtin_bit_cast(bf16x8, *(const uint4a*)(&sA[r * 64 + q * 8]));
            }
            #pragma unroll
            for (int j = 0; j < 4; ++j) {
                int r = wn + j * 16 + l15;
                int q = ((kk >> 3) + quad) ^ (r & 7);
                bfr[j] = __builtin_bit_cast(bf16x8, *(const uint4a*)(&sB[r * 64 + q * 8]));
            }
            #pragma unroll
            for (int i = 0; i < 4; ++i)
                #pragma unroll
                for (int j = 0; j < 4; ++j)
                    acc[i][j] = __builtin_amdgcn_mfma_f32_16x16x32_bf16(af[i], bfr[j], acc[i][j], 0, 0, 0);
        }
        __syncthreads();
    }

    // epilogue
    #pragma unroll
    for (int i = 0; i < 4; ++i) {
        #pragma unroll
        for (int j = 0; j < 4; ++j) {
            int col = n0 + wn + j * 16 + l15;
            int three = col >> 10;
            int h = (col >> 6) & 15;
            int d = col & 63;
            int row0 = m0 + wm + i * 16 + quad * 4;
            int b = row0 >> 11, n = row0 & 2047;
            size_t bh = (size_t)(b * NH + h);
            if (three == 0) {
                // Q pre-scaled: flash computes p = exp2(S) with no per-elem fma
                uint32_t p01 = pk2bf(acc[i][j][0] * C1SCALE, acc[i][j][1] * C1SCALE);
                uint32_t p23 = pk2bf(acc[i][j][2] * C1SCALE, acc[i][j][3] * C1SCALE);
                size_t base = (bh * SEQ + n) * HD + d;
                Q[base]          = (unsigned short)p01;
                Q[base + HD]     = (unsigned short)(p01 >> 16);
                Q[base + 2 * HD] = (unsigned short)p23;
                Q[base + 3 * HD] = (unsigned short)(p23 >> 16);
            } else if (three == 1) {
                #pragma unroll
                for (int r = 0; r < 4; ++r) {
                    int pf = pfx[(b << 11) + n + r];
                    if (pf >= 0) Kc[(bh * SEQ + pf) * HD + d] = f2bf(acc[i][j][r]);
                }
            } else {
                #pragma unroll
                for (int r = 0; r < 4; ++r) {
                    int pf = pfx[(b << 11) + n + r];
                    if (pf >= 0) Vct[(bh * HD + d) * SEQ + pf] = f2bf(acc[i][j][r]);
                }
            }
        }
    }
}

// ---------------- GEMM 2: out = attn @ Wproj + bias (fp32 out) ------------
__global__ __launch_bounds__(256, 2)
void gemm_proj_kernel(const unsigned short* __restrict__ A,
                      const unsigned short* __restrict__ Bt,
                      const float* __restrict__ bias,
                      float* __restrict__ Out) {
    __shared__ __align__(16) unsigned short sA[128 * 64];
    __shared__ __align__(16) unsigned short sB[128 * 64];
    const int Kdim = 1024;
    int m0 = blockIdx.x * 128;
    int n0 = blockIdx.y * 128;
    int tid = threadIdx.x;
    int wave = tid >> 6, lane = tid & 63;
    int wm = (wave >> 1) * 64, wn = (wave & 1) * 64;
    int l15 = lane & 15, quad = lane >> 4;
    int lr = lane >> 3, lc8 = ((lane & 7) ^ lr) * 8;

    f32x4 acc[4][4] = {};

    for (int k0 = 0; k0 < Kdim; k0 += BK) {
        #pragma unroll
        for (int it = 0; it < 4; ++it) {
            int c = wave * 4 + it;
            int gr = c * 8 + lr;
            g2l16(A  + (size_t)(m0 + gr) * Kdim + k0 + lc8, &sA[c * 512]);
            g2l16(Bt + (size_t)(n0 + gr) * Kdim + k0 + lc8, &sB[c * 512]);
        }
        __syncthreads();
        #pragma unroll
        for (int kk = 0; kk < BK; kk += 32) {
            bf16x8 af[4], bfr[4];
            #pragma unroll
            for (int i = 0; i < 4; ++i) {
                int r = wm + i * 16 + l15;
                int q = ((kk >> 3) + quad) ^ (r & 7);
                af[i] = __builtin_bit_cast(bf16x8, *(const uint4a*)(&sA[r * 64 + q * 8]));
            }
            #pragma unroll
            for (int j = 0; j < 4; ++j) {
                int r = wn + j * 16 + l15;
                int q = ((kk >> 3) + quad) ^ (r & 7);
                bfr[j] = __builtin_bit_cast(bf16x8, *(const uint4a*)(&sB[r * 64 + q * 8]));
            }
            #pragma unroll
            for (int i = 0; i < 4; ++i)
                #pragma unroll
                for (int j = 0; j < 4; ++j)
                    acc[i][j] = __builtin_amdgcn_mfma_f32_16x16x32_bf16(af[i], bfr[j], acc[i][j], 0, 0, 0);
        }
        __syncthreads();
    }

    #pragma unroll
    for (int i = 0; i < 4; ++i) {
        #pragma unroll
        for (int j = 0; j < 4; ++j) {
            int col = n0 + wn + j * 16 + l15;
            float bv = bias[col];
            #pragma unroll
            for (int r = 0; r < 4; ++r) {
                int row = m0 + wm + i * 16 + quad * 4 + r;
                Out[(size_t)row * CDIM + col] = acc[i][j][r] + bv;
            }
        }
    }
}

// ---------------- Flash attention v7 ---------------------------------------
// Q pre-scaled by C1SCALE -> main loop p = exp2(S), no fma/mask (compacted
// keys; mask only matters in the final partial tile -> uniform tail branch).
// Row-sum l computed by ones-column MFMA into oextra (C-layout slot matches
// oacc rows -> no shuffle reduction).
#define SPD 72   /* sP row stride (shorts), 144B rows (16B aligned) */

__global__ __launch_bounds__(256, 4)
void flash_attn_kernel(const unsigned short* __restrict__ Q,
                       const unsigned short* __restrict__ Kg,
                       const unsigned short* __restrict__ Vt,
                       const int* __restrict__ cnt,
                       unsigned short* __restrict__ O) {
    int bh = blockIdx.x;
    int q0 = blockIdx.y * 128;
    int b = bh >> 4, h = bh & 15;
    int tid = threadIdx.x;
    int wave = tid >> 6, lane = tid & 63;
    int l15 = lane & 15, quad = lane >> 4;
    int lr = lane >> 3, lc8 = ((lane & 7) ^ lr) * 8;

    const int kn = cnt[b];

    const size_t head_off = (size_t)bh * SEQ * HD;
    const unsigned short* Qh = Q + head_off;
    const unsigned short* Kh = Kg + head_off;
    const unsigned short* Vh = Vt + head_off;   // [HD][SEQ]

    __shared__ __align__(16) unsigned short sK [64 * 64];
    __shared__ __align__(16) unsigned short sVt[64 * 64];
    __shared__ __align__(16) unsigned short sP [4][16 * SPD];  // per-wave

    bf16x8 qf[2][2];
    #pragma unroll
    for (int mt = 0; mt < 2; ++mt) {
        const unsigned short* qp = Qh + (size_t)(q0 + wave * 32 + mt * 16 + l15) * HD + quad * 8;
        qf[mt][0] = __builtin_bit_cast(bf16x8, *(const uint4a*)(qp));
        qf[mt][1] = __builtin_bit_cast(bf16x8, *(const uint4a*)(qp + 32));
    }

    // all-ones B fragment for the l row-sum MFMA
    bf16x8 ones;
    {
        uint4 ov;
        ov.x = ov.y = ov.z = ov.w = 0x3F803F80u;
        ones = __builtin_bit_cast(bf16x8, ov);
    }

    f32x4 oacc[2][4] = {};
    f32x4 oextra[2] = {};   // oextra[mt][r] = l[row] (ones-column MFMA)

    for (int k0 = 0; k0 < kn; k0 += 64) {
        // async-stage K rows and V^T rows (64x64 each), swizzled
        #pragma unroll
        for (int it = 0; it < 2; ++it) {
            int c = wave * 2 + it;
            int gr = c * 8 + lr;
            g2l16(Kh + (size_t)(k0 + gr) * HD + lc8, &sK[c * 512]);
            g2l16(Vh + (size_t)gr * SEQ + k0 + lc8, &sVt[c * 512]);
        }
        __syncthreads();

        bool tail = (k0 + 64 > kn);   // block-uniform

        #pragma unroll
        for (int mt = 0; mt < 2; ++mt) {
            // S = Q K^T  (16 q x 64 k), S pre-scaled via Q
            f32x4 s[4] = {};
            #pragma unroll
            for (int j = 0; j < 4; ++j) {
                int r = j * 16 + l15, sw = r & 7;
                uint4 v0 = *(const uint4a*)(&sK[r * 64 + ((quad ^ sw) * 8)]);
                uint4 v1 = *(const uint4a*)(&sK[r * 64 + (((4 + quad) ^ sw) * 8)]);
                s[j] = __builtin_amdgcn_mfma_f32_16x16x32_bf16(qf[mt][0], __builtin_bit_cast(bf16x8, v0), s[j], 0, 0, 0);
                s[j] = __builtin_amdgcn_mfma_f32_16x16x32_bf16(qf[mt][1], __builtin_bit_cast(bf16x8, v1), s[j], 0, 0, 0);
            }
            // p = exp2(S) (+ -1e30 for out-of-range cols, tail tile only)
            unsigned short* sp = &sP[wave][0];
            if (tail) {
                #pragma unroll
                for (int j = 0; j < 4; ++j) {
                    float madd = (k0 + j * 16 + l15 < kn) ? 0.f : -1e30f;
                    #pragma unroll
                    for (int r = 0; r < 4; ++r)
                        s[j][r] = __builtin_amdgcn_exp2f(s[j][r] + madd);
                }
            } else {
                #pragma unroll
                for (int j = 0; j < 4; ++j)
                    #pragma unroll
                    for (int r = 0; r < 4; ++r)
                        s[j][r] = __builtin_amdgcn_exp2f(s[j][r]);
            }
            #pragma unroll
            for (int j = 0; j < 4; ++j) {
                uint32_t p01 = pk2bf(s[j][0], s[j][1]);
                uint32_t p23 = pk2bf(s[j][2], s[j][3]);
                int base = quad * 4 * SPD + j * 16 + l15;
                sp[base]           = (unsigned short)p01;
                sp[base + SPD]     = (unsigned short)(p01 >> 16);
                sp[base + 2 * SPD] = (unsigned short)p23;
                sp[base + 3 * SPD] = (unsigned short)(p23 >> 16);
            }
            // O += P V;  l += P 1  (per-wave sP: in-order DS pipe, RAW safe)
            #pragma unroll
            for (int kc = 0; kc < 2; ++kc) {
                uint4 av = *(const uint4a*)(&sp[l15 * SPD + kc * 32 + quad * 8]);
                bf16x8 af = __builtin_bit_cast(bf16x8, av);
                #pragma unroll
                for (int jd = 0; jd < 4; ++jd) {
                    int r = jd * 16 + l15;
                    int q = ((kc * 4 + quad) ^ (r & 7)) * 8;
                    uint4 bv = *(const uint4a*)(&sVt[r * 64 + q]);
                    oacc[mt][jd] = __builtin_amdgcn_mfma_f32_16x16x32_bf16(af, __builtin_bit_cast(bf16x8, bv), oacc[mt][jd], 0, 0, 0);
                }
                oextra[mt] = __builtin_amdgcn_mfma_f32_16x16x32_bf16(af, ones, oextra[mt], 0, 0, 0);
            }
        }
        __syncthreads();
    }

    // epilogue: O *= 1/l, write [B,N,C] bf16  (oextra[r] holds l[row] in-lane)
    #pragma unroll
    for (int mt = 0; mt < 2; ++mt) {
        float rl[4];
        #pragma unroll
        for (int r = 0; r < 4; ++r) rl[r] = __builtin_amdgcn_rcpf(oextra[mt][r]);
        #pragma unroll
        for (int jd = 0; jd < 4; ++jd) {
            int d = jd * 16 + l15;
            size_t base = ((size_t)(b * SEQ + q0 + wave * 32 + mt * 16 + quad * 4)) * CDIM + h * HD + d;
            uint32_t p01 = pk2bf(oacc[mt][jd][0] * rl[0], oacc[mt][jd][1] * rl[1]);
            uint32_t p23 = pk2bf(oacc[mt][jd][2] * rl[2], oacc[mt][jd][3] * rl[3]);
            O[base]            = (unsigned short)p01;
            O[base + CDIM]     = (unsigned short)(p01 >> 16);
            O[base + 2 * CDIM] = (unsigned short)p23;
            O[base + 3 * CDIM] = (unsigned short)(p23 >> 16);
        }
    }
}

extern "C" void kernel_launch(void* const* d_in, const int* in_sizes, int n_in,
                              void* d_out, int out_size, void* d_ws, size_t ws_size,
                              hipStream_t stream) {
    const float* x     = (const float*)d_in[0];
    const float* Wqkv  = (const float*)d_in[1];
    const float* Wproj = (const float*)d_in[2];
    const float* bproj = (const float*)d_in[3];
    const int*   mask  = (const int*)d_in[4];
    float* out = (float*)d_out;

    char* ws = (char*)d_ws;
    unsigned short* xb     = (unsigned short*)(ws);                       // 16 MB (also attn out)
    unsigned short* Wqkvt  = (unsigned short*)(ws + (16u << 20));         // 6 MB
    unsigned short* Wprojt = (unsigned short*)(ws + (22u << 20));         // 2 MB
    unsigned short* Qb     = (unsigned short*)(ws + (24u << 20));         // 16 MB
    unsigned short* Kb     = (unsigned short*)(ws + (40u << 20));         // 16 MB
    unsigned short* Vtb    = (unsigned short*)(ws + (56u << 20));         // 16 MB, ends 72 MB
    int*            pfx    = (int*)(ws + (72u << 20));                    // 32 KB
    int*            cntb   = (int*)(ws + (72u << 20) + (32u << 10));      // 16 B

    cvt_bf16_kernel<<<dim3(8192), dim3(256), 0, stream>>>(x, xb, MROWS * CDIM);
    transpose_cvt_kernel<<<dim3(96, 32), dim3(32, 8), 0, stream>>>(Wqkv, Wqkvt, 1024, 3072);
    transpose_cvt_kernel<<<dim3(32, 32), dim3(32, 8), 0, stream>>>(Wproj, Wprojt, 1024, 1024);
    mask_scan_kernel<<<dim3(4), dim3(256), 0, stream>>>(mask, pfx, cntb);
    gemm_qkv_kernel<<<dim3(64, 24), dim3(256), 0, stream>>>(xb, Wqkvt, pfx, Qb, Kb, Vtb);
    flash_attn_kernel<<<dim3(64, 16), dim3(256), 0, stream>>>(Qb, Kb, Vtb, cntb, xb);
    gemm_proj_kernel<<<dim3(64, 8), dim3(256), 0, stream>>>(xb, Wprojt, bproj, out);
}

// Round 8
// 244.775 us; speedup vs baseline: 1.0426x; 1.0426x over previous
//
#include <hip/hip_runtime.h>
#include <hip/hip_bf16.h>
#include <cstdint>

typedef __bf16 bf16x8 __attribute__((ext_vector_type(8)));
typedef float f32x4 __attribute__((ext_vector_type(4)));
typedef uint4 __attribute__((may_alias)) uint4a;

typedef __attribute__((address_space(3))) unsigned int   lds_u32;
typedef __attribute__((address_space(1))) const unsigned int gbl_u32;

#define BATCH 4
#define SEQ   2048
#define CDIM  1024
#define NH    16
#define HD    64
#define MROWS (BATCH*SEQ)   /* 8192 */

#define C1SCALE 0.18033688011112042f  /* Dh^-0.5 * log2(e), folded into Q */

__device__ __forceinline__ unsigned short f2bf(float f) {
    uint32_t u = __builtin_bit_cast(uint32_t, f);
    u += 0x7fffu + ((u >> 16) & 1u);
    return (unsigned short)(u >> 16);
}

// packed f32x2 -> bf16x2 (low = a, high = b), HW instr on gfx950
#if __has_builtin(__builtin_amdgcn_cvt_pk_bf16_f32)
typedef __bf16 bf16x2 __attribute__((ext_vector_type(2)));
__device__ __forceinline__ uint32_t pk2bf(float a, float b) {
    bf16x2 v = __builtin_amdgcn_cvt_pk_bf16_f32(a, b);
    return __builtin_bit_cast(uint32_t, v);
}
#else
__device__ __forceinline__ uint32_t pk2bf(float a, float b) {
    return (uint32_t)f2bf(a) | ((uint32_t)f2bf(b) << 16);
}
#endif

// async 16B/lane global->LDS (wave-uniform LDS base; HW writes base+lane*16)
__device__ __forceinline__ void g2l16(const unsigned short* g, unsigned short* l) {
    __builtin_amdgcn_global_load_lds((gbl_u32*)g, (lds_u32*)l, 16, 0, 0);
}

// ---------------- fused prep: cvt(x) + transpose(Wqkv) + transpose(Wproj)
// ---------------- + mask scan, partitioned by blockIdx.x (block-uniform)
#define NB_CVT   8192                 /* 8192 blocks * 1024 elems */
#define NB_TQKV  3072                 /* 96 x 32 tiles */
#define NB_TPROJ 1024                 /* 32 x 32 tiles */
#define NB_PREP  (NB_CVT + NB_TQKV + NB_TPROJ + 4)

__global__ __launch_bounds__(256)
void prep_kernel(const float* __restrict__ x,
                 const float* __restrict__ Wqkv,
                 const float* __restrict__ Wproj,
                 const int* __restrict__ mask,
                 unsigned short* __restrict__ xb,
                 unsigned short* __restrict__ Wqkvt,
                 unsigned short* __restrict__ Wprojt,
                 int* __restrict__ pfx, int* __restrict__ cnt) {
    __shared__ float tile[32][33];
    __shared__ int s[256];
    int bid = blockIdx.x, tid = threadIdx.x;

    if (bid < NB_CVT) {
        // fp32 -> bf16 elementwise on x
        int i = (bid * 256 + tid) * 4;
        float4 v = *(const float4*)(x + i);
        uint2 o;
        o.x = pk2bf(v.x, v.y);
        o.y = pk2bf(v.z, v.w);
        *(uint2*)(xb + i) = o;
        return;
    }
    if (bid < NB_CVT + NB_TQKV + NB_TPROJ) {
        // transpose + cvt: W[R=1024][Cc] -> Wt[Cc][1024]
        const float* in;
        unsigned short* out;
        int Cc, bx;
        if (bid < NB_CVT + NB_TQKV) {
            bx = bid - NB_CVT; in = Wqkv; out = Wqkvt; Cc = 3072;
        } else {
            bx = bid - NB_CVT - NB_TQKV; in = Wproj; out = Wprojt; Cc = 1024;
        }
        int nbx = Cc >> 5;
        int c0 = (bx % nbx) * 32, r0 = (bx / nbx) * 32;
        int tx = tid & 31, ty = tid >> 5;
        #pragma unroll
        for (int i = 0; i < 32; i += 8)
            tile[ty + i][tx] = in[(size_t)(r0 + ty + i) * Cc + c0 + tx];
        __syncthreads();
        #pragma unroll
        for (int i = 0; i < 32; i += 8)
            out[(size_t)(c0 + ty + i) * 1024 + r0 + tx] = f2bf(tile[tx][ty + i]);
        return;
    }
    // per-batch mask compaction scan
    int b = bid - (NB_CVT + NB_TQKV + NB_TPROJ);
    int keep[8], lc = 0;
    #pragma unroll
    for (int u = 0; u < 8; ++u) {
        keep[u] = (mask[b * SEQ + tid * 8 + u] > 0) ? 0 : 1;
        lc += keep[u];
    }
    s[tid] = lc;
    __syncthreads();
    for (int d = 1; d < 256; d <<= 1) {
        int w = (tid >= d) ? s[tid - d] : 0;
        __syncthreads();
        s[tid] += w;
        __syncthreads();
    }
    int pos = s[tid] - lc;
    #pragma unroll
    for (int u = 0; u < 8; ++u) {
        int idx = b * SEQ + tid * 8 + u;
        pfx[idx] = keep[u] ? pos++ : -1;
    }
    if (tid == 255) cnt[b] = s[255];
}

// ---------------- GEMM 1: qkv = xb @ Wqkv --------------------------------
// Q -> [B,H,N,Dh] PRE-SCALED by C1SCALE; K -> [B,H,j,Dh] compacted;
// V -> [B,H,Dh,j] compacted+T.
// LDS: stride 64 shorts, 16B-granule XOR swizzle (conflict-free reads).
#define BK 64

__global__ __launch_bounds__(256, 2)
void gemm_qkv_kernel(const unsigned short* __restrict__ A,
                     const unsigned short* __restrict__ Bt,
                     const int* __restrict__ pfx,
                     unsigned short* __restrict__ Q,
                     unsigned short* __restrict__ Kc,
                     unsigned short* __restrict__ Vct) {
    __shared__ __align__(16) unsigned short sA[128 * 64];
    __shared__ __align__(16) unsigned short sB[128 * 64];
    const int Kdim = 1024;
    int m0 = blockIdx.x * 128;
    int n0 = blockIdx.y * 128;
    int tid = threadIdx.x;
    int wave = tid >> 6, lane = tid & 63;
    int wm = (wave >> 1) * 64, wn = (wave & 1) * 64;
    int l15 = lane & 15, quad = lane >> 4;
    int lr = lane >> 3, lc8 = ((lane & 7) ^ lr) * 8;  // swizzled source col

    f32x4 acc[4][4] = {};

    for (int k0 = 0; k0 < Kdim; k0 += BK) {
        #pragma unroll
        for (int it = 0; it < 4; ++it) {
            int c = wave * 4 + it;            // chunk: 8 rows x 64 cols
            int gr = c * 8 + lr;
            g2l16(A  + (size_t)(m0 + gr) * Kdim + k0 + lc8, &sA[c * 512]);
            g2l16(Bt + (size_t)(n0 + gr) * Kdim + k0 + lc8, &sB[c * 512]);
        }
        __syncthreads();
        #pragma unroll
        for (int kk = 0; kk < BK; kk += 32) {
            bf16x8 af[4], bfr[4];
            #pragma unroll
            for (int i = 0; i < 4; ++i) {
                int r = wm + i * 16 + l15;
                int q = ((kk >> 3) + quad) ^ (r & 7);
                af[i] = __builtin_bit_cast(bf16x8, *(const uint4a*)(&sA[r * 64 + q * 8]));
            }
            #pragma unroll
            for (int j = 0; j < 4; ++j) {
                int r = wn + j * 16 + l15;
                int q = ((kk >> 3) + quad) ^ (r & 7);
                bfr[j] = __builtin_bit_cast(bf16x8, *(const uint4a*)(&sB[r * 64 + q * 8]));
            }
            #pragma unroll
            for (int i = 0; i < 4; ++i)
                #pragma unroll
                for (int j = 0; j < 4; ++j)
                    acc[i][j] = __builtin_amdgcn_mfma_f32_16x16x32_bf16(af[i], bfr[j], acc[i][j], 0, 0, 0);
        }
        __syncthreads();
    }

    // epilogue
    #pragma unroll
    for (int i = 0; i < 4; ++i) {
        #pragma unroll
        for (int j = 0; j < 4; ++j) {
            int col = n0 + wn + j * 16 + l15;
            int three = col >> 10;
            int h = (col >> 6) & 15;
            int d = col & 63;
            int row0 = m0 + wm + i * 16 + quad * 4;
            int b = row0 >> 11, n = row0 & 2047;
            size_t bh = (size_t)(b * NH + h);
            if (three == 0) {
                // Q pre-scaled: flash computes p = exp2(S) with no per-elem fma
                uint32_t p01 = pk2bf(acc[i][j][0] * C1SCALE, acc[i][j][1] * C1SCALE);
                uint32_t p23 = pk2bf(acc[i][j][2] * C1SCALE, acc[i][j][3] * C1SCALE);
                size_t base = (bh * SEQ + n) * HD + d;
                Q[base]          = (unsigned short)p01;
                Q[base + HD]     = (unsigned short)(p01 >> 16);
                Q[base + 2 * HD] = (unsigned short)p23;
                Q[base + 3 * HD] = (unsigned short)(p23 >> 16);
            } else if (three == 1) {
                #pragma unroll
                for (int r = 0; r < 4; ++r) {
                    int pf = pfx[(b << 11) + n + r];
                    if (pf >= 0) Kc[(bh * SEQ + pf) * HD + d] = f2bf(acc[i][j][r]);
                }
            } else {
                #pragma unroll
                for (int r = 0; r < 4; ++r) {
                    int pf = pfx[(b << 11) + n + r];
                    if (pf >= 0) Vct[(bh * HD + d) * SEQ + pf] = f2bf(acc[i][j][r]);
                }
            }
        }
    }
}

// ---------------- GEMM 2: out = attn @ Wproj + bias (fp32 out) ------------
__global__ __launch_bounds__(256, 2)
void gemm_proj_kernel(const unsigned short* __restrict__ A,
                      const unsigned short* __restrict__ Bt,
                      const float* __restrict__ bias,
                      float* __restrict__ Out) {
    __shared__ __align__(16) unsigned short sA[128 * 64];
    __shared__ __align__(16) unsigned short sB[128 * 64];
    const int Kdim = 1024;
    int m0 = blockIdx.x * 128;
    int n0 = blockIdx.y * 128;
    int tid = threadIdx.x;
    int wave = tid >> 6, lane = tid & 63;
    int wm = (wave >> 1) * 64, wn = (wave & 1) * 64;
    int l15 = lane & 15, quad = lane >> 4;
    int lr = lane >> 3, lc8 = ((lane & 7) ^ lr) * 8;

    f32x4 acc[4][4] = {};

    for (int k0 = 0; k0 < Kdim; k0 += BK) {
        #pragma unroll
        for (int it = 0; it < 4; ++it) {
            int c = wave * 4 + it;
            int gr = c * 8 + lr;
            g2l16(A  + (size_t)(m0 + gr) * Kdim + k0 + lc8, &sA[c * 512]);
            g2l16(Bt + (size_t)(n0 + gr) * Kdim + k0 + lc8, &sB[c * 512]);
        }
        __syncthreads();
        #pragma unroll
        for (int kk = 0; kk < BK; kk += 32) {
            bf16x8 af[4], bfr[4];
            #pragma unroll
            for (int i = 0; i < 4; ++i) {
                int r = wm + i * 16 + l15;
                int q = ((kk >> 3) + quad) ^ (r & 7);
                af[i] = __builtin_bit_cast(bf16x8, *(const uint4a*)(&sA[r * 64 + q * 8]));
            }
            #pragma unroll
            for (int j = 0; j < 4; ++j) {
                int r = wn + j * 16 + l15;
                int q = ((kk >> 3) + quad) ^ (r & 7);
                bfr[j] = __builtin_bit_cast(bf16x8, *(const uint4a*)(&sB[r * 64 + q * 8]));
            }
            #pragma unroll
            for (int i = 0; i < 4; ++i)
                #pragma unroll
                for (int j = 0; j < 4; ++j)
                    acc[i][j] = __builtin_amdgcn_mfma_f32_16x16x32_bf16(af[i], bfr[j], acc[i][j], 0, 0, 0);
        }
        __syncthreads();
    }

    #pragma unroll
    for (int i = 0; i < 4; ++i) {
        #pragma unroll
        for (int j = 0; j < 4; ++j) {
            int col = n0 + wn + j * 16 + l15;
            float bv = bias[col];
            #pragma unroll
            for (int r = 0; r < 4; ++r) {
                int row = m0 + wm + i * 16 + quad * 4 + r;
                Out[(size_t)row * CDIM + col] = acc[i][j][r] + bv;
            }
        }
    }
}

// ---------------- Flash attention v7 ---------------------------------------
// Q pre-scaled by C1SCALE -> main loop p = exp2(S); compacted keys; mask only
// in final partial tile (uniform tail branch). Row-sum l via ones-column MFMA.
#define SPD 72   /* sP row stride (shorts), 144B rows (16B aligned) */

__global__ __launch_bounds__(256, 4)
void flash_attn_kernel(const unsigned short* __restrict__ Q,
                       const unsigned short* __restrict__ Kg,
                       const unsigned short* __restrict__ Vt,
                       const int* __restrict__ cnt,
                       unsigned short* __restrict__ O) {
    int bh = blockIdx.x;
    int q0 = blockIdx.y * 128;
    int b = bh >> 4, h = bh & 15;
    int tid = threadIdx.x;
    int wave = tid >> 6, lane = tid & 63;
    int l15 = lane & 15, quad = lane >> 4;
    int lr = lane >> 3, lc8 = ((lane & 7) ^ lr) * 8;

    const int kn = cnt[b];

    const size_t head_off = (size_t)bh * SEQ * HD;
    const unsigned short* Qh = Q + head_off;
    const unsigned short* Kh = Kg + head_off;
    const unsigned short* Vh = Vt + head_off;   // [HD][SEQ]

    __shared__ __align__(16) unsigned short sK [64 * 64];
    __shared__ __align__(16) unsigned short sVt[64 * 64];
    __shared__ __align__(16) unsigned short sP [4][16 * SPD];  // per-wave

    bf16x8 qf[2][2];
    #pragma unroll
    for (int mt = 0; mt < 2; ++mt) {
        const unsigned short* qp = Qh + (size_t)(q0 + wave * 32 + mt * 16 + l15) * HD + quad * 8;
        qf[mt][0] = __builtin_bit_cast(bf16x8, *(const uint4a*)(qp));
        qf[mt][1] = __builtin_bit_cast(bf16x8, *(const uint4a*)(qp + 32));
    }

    // all-ones B fragment for the l row-sum MFMA
    bf16x8 ones;
    {
        uint4 ov;
        ov.x = ov.y = ov.z = ov.w = 0x3F803F80u;
        ones = __builtin_bit_cast(bf16x8, ov);
    }

    f32x4 oacc[2][4] = {};
    f32x4 oextra[2] = {};   // oextra[mt][r] = l[row] (ones-column MFMA)

    for (int k0 = 0; k0 < kn; k0 += 64) {
        // async-stage K rows and V^T rows (64x64 each), swizzled
        #pragma unroll
        for (int it = 0; it < 2; ++it) {
            int c = wave * 2 + it;
            int gr = c * 8 + lr;
            g2l16(Kh + (size_t)(k0 + gr) * HD + lc8, &sK[c * 512]);
            g2l16(Vh + (size_t)gr * SEQ + k0 + lc8, &sVt[c * 512]);
        }
        __syncthreads();

        bool tail = (k0 + 64 > kn);   // block-uniform

        #pragma unroll
        for (int mt = 0; mt < 2; ++mt) {
            // S = Q K^T  (16 q x 64 k), S pre-scaled via Q
            f32x4 s[4] = {};
            #pragma unroll
            for (int j = 0; j < 4; ++j) {
                int r = j * 16 + l15, sw = r & 7;
                uint4 v0 = *(const uint4a*)(&sK[r * 64 + ((quad ^ sw) * 8)]);
                uint4 v1 = *(const uint4a*)(&sK[r * 64 + (((4 + quad) ^ sw) * 8)]);
                s[j] = __builtin_amdgcn_mfma_f32_16x16x32_bf16(qf[mt][0], __builtin_bit_cast(bf16x8, v0), s[j], 0, 0, 0);
                s[j] = __builtin_amdgcn_mfma_f32_16x16x32_bf16(qf[mt][1], __builtin_bit_cast(bf16x8, v1), s[j], 0, 0, 0);
            }
            // p = exp2(S) (+ -1e30 for out-of-range cols, tail tile only)
            unsigned short* sp = &sP[wave][0];
            if (tail) {
                #pragma unroll
                for (int j = 0; j < 4; ++j) {
                    float madd = (k0 + j * 16 + l15 < kn) ? 0.f : -1e30f;
                    #pragma unroll
                    for (int r = 0; r < 4; ++r)
                        s[j][r] = __builtin_amdgcn_exp2f(s[j][r] + madd);
                }
            } else {
                #pragma unroll
                for (int j = 0; j < 4; ++j)
                    #pragma unroll
                    for (int r = 0; r < 4; ++r)
                        s[j][r] = __builtin_amdgcn_exp2f(s[j][r]);
            }
            #pragma unroll
            for (int j = 0; j < 4; ++j) {
                uint32_t p01 = pk2bf(s[j][0], s[j][1]);
                uint32_t p23 = pk2bf(s[j][2], s[j][3]);
                int base = quad * 4 * SPD + j * 16 + l15;
                sp[base]           = (unsigned short)p01;
                sp[base + SPD]     = (unsigned short)(p01 >> 16);
                sp[base + 2 * SPD] = (unsigned short)p23;
                sp[base + 3 * SPD] = (unsigned short)(p23 >> 16);
            }
            // O += P V;  l += P 1  (per-wave sP: in-order DS pipe, RAW safe)
            #pragma unroll
            for (int kc = 0; kc < 2; ++kc) {
                uint4 av = *(const uint4a*)(&sp[l15 * SPD + kc * 32 + quad * 8]);
                bf16x8 af = __builtin_bit_cast(bf16x8, av);
                #pragma unroll
                for (int jd = 0; jd < 4; ++jd) {
                    int r = jd * 16 + l15;
                    int q = ((kc * 4 + quad) ^ (r & 7)) * 8;
                    uint4 bv = *(const uint4a*)(&sVt[r * 64 + q]);
                    oacc[mt][jd] = __builtin_amdgcn_mfma_f32_16x16x32_bf16(af, __builtin_bit_cast(bf16x8, bv), oacc[mt][jd], 0, 0, 0);
                }
                oextra[mt] = __builtin_amdgcn_mfma_f32_16x16x32_bf16(af, ones, oextra[mt], 0, 0, 0);
            }
        }
        __syncthreads();
    }

    // epilogue: O *= 1/l, write [B,N,C] bf16  (oextra[r] holds l[row] in-lane)
    #pragma unroll
    for (int mt = 0; mt < 2; ++mt) {
        float rl[4];
        #pragma unroll
        for (int r = 0; r < 4; ++r) rl[r] = __builtin_amdgcn_rcpf(oextra[mt][r]);
        #pragma unroll
        for (int jd = 0; jd < 4; ++jd) {
            int d = jd * 16 + l15;
            size_t base = ((size_t)(b * SEQ + q0 + wave * 32 + mt * 16 + quad * 4)) * CDIM + h * HD + d;
            uint32_t p01 = pk2bf(oacc[mt][jd][0] * rl[0], oacc[mt][jd][1] * rl[1]);
            uint32_t p23 = pk2bf(oacc[mt][jd][2] * rl[2], oacc[mt][jd][3] * rl[3]);
            O[base]            = (unsigned short)p01;
            O[base + CDIM]     = (unsigned short)(p01 >> 16);
            O[base + 2 * CDIM] = (unsigned short)p23;
            O[base + 3 * CDIM] = (unsigned short)(p23 >> 16);
        }
    }
}

extern "C" void kernel_launch(void* const* d_in, const int* in_sizes, int n_in,
                              void* d_out, int out_size, void* d_ws, size_t ws_size,
                              hipStream_t stream) {
    const float* x     = (const float*)d_in[0];
    const float* Wqkv  = (const float*)d_in[1];
    const float* Wproj = (const float*)d_in[2];
    const float* bproj = (const float*)d_in[3];
    const int*   mask  = (const int*)d_in[4];
    float* out = (float*)d_out;

    char* ws = (char*)d_ws;
    unsigned short* xb     = (unsigned short*)(ws);                       // 16 MB (also attn out)
    unsigned short* Wqkvt  = (unsigned short*)(ws + (16u << 20));         // 6 MB
    unsigned short* Wprojt = (unsigned short*)(ws + (22u << 20));         // 2 MB
    unsigned short* Qb     = (unsigned short*)(ws + (24u << 20));         // 16 MB
    unsigned short* Kb     = (unsigned short*)(ws + (40u << 20));         // 16 MB
    unsigned short* Vtb    = (unsigned short*)(ws + (56u << 20));         // 16 MB, ends 72 MB
    int*            pfx    = (int*)(ws + (72u << 20));                    // 32 KB
    int*            cntb   = (int*)(ws + (72u << 20) + (32u << 10));      // 16 B

    prep_kernel<<<dim3(NB_PREP), dim3(256), 0, stream>>>(x, Wqkv, Wproj, mask,
                                                         xb, Wqkvt, Wprojt, pfx, cntb);
    gemm_qkv_kernel<<<dim3(64, 24), dim3(256), 0, stream>>>(xb, Wqkvt, pfx, Qb, Kb, Vtb);
    flash_attn_kernel<<<dim3(64, 16), dim3(256), 0, stream>>>(Qb, Kb, Vtb, cntb, xb);
    gemm_proj_kernel<<<dim3(64, 8), dim3(256), 0, stream>>>(xb, Wprojt, bproj, out);
}